// Round 7
// baseline (197.554 us; speedup 1.0000x reference)
//
#include <hip/hip_runtime.h>
#include <hip/hip_bf16.h>
#include <math.h>

// Problem: B=16, K=256, D=128, H=64
//   hi[b,k,h] = particles[b,k,:] @ W1[:D, h] + b1[h]   (b1 folded here)
//   hj[b,k,h] = particles[b,k,:] @ W1[D:, h]
//   sd[b,i,j] = sum_h gelu(hi[b,i,h] + hj[b,j,h]) * W2[h] + b2
//   loss = mean((sd - true_dist)^2)
// Output: [sd flattened (16*256*256 floats)] [loss (1 float)]

#define Bn 16
#define Kn 256
#define Dn 128
#define Hn 64
#define NBLK 2048   // kB grid: 8 x 16 x 16

typedef float f32x2 __attribute__((ext_vector_type(2)));
typedef int   i32x2 __attribute__((ext_vector_type(2)));

// Trans-free fast GELU on 2 lanes of packed f32.
//   gelu(x) ~= x * sigmoid(2.3022082*x*(1+0.044715 x^2))
//   exp2 via Schraudolph bit-trick; cubic pre-scaled by 2^23 (folds one mul):
//     u = x*(c1*2^23*x^2 + c0*2^23) + (127-0.0436)*2^23
//   rcp via magic-constant + 1 Newton step (~0.13% rel)
__device__ __forceinline__ void gelu_dot2(f32x2 a, f32x2 c, f32x2 w, f32x2& acc) {
    f32x2 x  = a + c;
    f32x2 x2 = x * x;
    f32x2 t1 = __builtin_elementwise_fma(x2, (f32x2)(-863592.7f), (f32x2)(-19312322.0f));
    f32x2 u  = __builtin_elementwise_fma(x, t1, (f32x2)1064987473.0f);
    i32x2 iu = __builtin_convertvector(u, i32x2);          // u > 0 always
    f32x2 e  = __builtin_bit_cast(f32x2, iu);              // ~2^t, t<=0 -> e in (0,1]
    f32x2 d  = e + 1.0f;
    i32x2 id = __builtin_bit_cast(i32x2, d);
    i32x2 ir = 0x7EF311C3 - id;
    f32x2 r0 = __builtin_bit_cast(f32x2, ir);
    f32x2 q  = __builtin_elementwise_fma(-d, r0, (f32x2)2.0f);
    f32x2 r  = r0 * q;
    f32x2 g  = x * r;                                      // x * sigmoid
    acc = __builtin_elementwise_fma(g, w, acc);
}

// ---------------- Kernel A: hi/hj precompute (also zeroes kB's done-counter) ----------------
__global__ __launch_bounds__(256) void kA(const float* __restrict__ particles,
                                          const float* __restrict__ W1,
                                          const float* __restrict__ b1,
                                          float* __restrict__ hi,
                                          float* __restrict__ hj,
                                          unsigned* __restrict__ counter) {
    __shared__ __align__(16) float w1a[Dn * Hn];   // 32 KB  W1[:128]
    __shared__ __align__(16) float w1b[Dn * Hn];   // 32 KB  W1[128:]
    __shared__ __align__(16) float ps[16][Dn];     // 8 KB
    __shared__ __align__(16) float b1s[Hn];

    const int tid = threadIdx.x;
    const int row0 = blockIdx.x * 16;

    if (blockIdx.x == 0 && tid == 0) counter[0] = 0;   // visible to kB (end-of-kernel release)

    for (int idx = tid; idx < (Dn * Hn) / 4; idx += 256) {
        ((float4*)w1a)[idx] = ((const float4*)W1)[idx];
        ((float4*)w1b)[idx] = ((const float4*)(W1 + Dn * Hn))[idx];
    }
    for (int idx = tid; idx < (16 * Dn) / 4; idx += 256)
        ((float4*)&ps[0][0])[idx] = ((const float4*)(particles + row0 * Dn))[idx];
    if (tid < Hn / 4)
        ((float4*)b1s)[tid] = ((const float4*)b1)[tid];
    __syncthreads();

    const int r  = tid >> 4;
    const int h0 = (tid & 15) * 4;

    float4 ai = {0.f, 0.f, 0.f, 0.f};
    float4 aj = {0.f, 0.f, 0.f, 0.f};
#pragma unroll 8
    for (int d = 0; d < Dn; ++d) {
        const float p  = ps[r][d];
        const float4 wa = *(const float4*)&w1a[d * Hn + h0];
        const float4 wb = *(const float4*)&w1b[d * Hn + h0];
        ai.x = fmaf(p, wa.x, ai.x); ai.y = fmaf(p, wa.y, ai.y);
        ai.z = fmaf(p, wa.z, ai.z); ai.w = fmaf(p, wa.w, ai.w);
        aj.x = fmaf(p, wb.x, aj.x); aj.y = fmaf(p, wb.y, aj.y);
        aj.z = fmaf(p, wb.z, aj.z); aj.w = fmaf(p, wb.w, aj.w);
    }
    const float4 bb = *(const float4*)&b1s[h0];
    ai.x += bb.x; ai.y += bb.y; ai.z += bb.z; ai.w += bb.w;

    *(float4*)&hi[(row0 + r) * Hn + h0] = ai;
    *(float4*)&hj[(row0 + r) * Hn + h0] = aj;
}

// ---------------- Kernel B: main pairwise kernel + fused final reduction ----------------
// grid (K/32, K/16, B) = (8,16,16), 256 threads.
// Thread (ti = tid>>4, tj = tid&15) computes 2 outputs: j = jt*32 + tj and + 16.
// shi row read (ds_read_b128) is shared by both outputs. Last block reduces loss.
__global__ __launch_bounds__(256) void kB(const float* __restrict__ hi,
                                          const float* __restrict__ hj,
                                          const float* __restrict__ positions,
                                          const float* __restrict__ W2,
                                          const float* __restrict__ b2,
                                          float* __restrict__ out,
                                          float* __restrict__ partials,
                                          unsigned* __restrict__ counter,
                                          float* __restrict__ loss_out) {
    __shared__ __align__(16) float shi[16][68];
    __shared__ __align__(16) float shj[32][68];
    __shared__ float pix[16], piy[16], pjx[32], pjy[32];
    __shared__ float wsum[4];
    __shared__ int last;

    const int jt = blockIdx.x, it = blockIdx.y, b = blockIdx.z;
    const int tid = threadIdx.x;

    {   // stage: shi 256 float4 (1/thread), shj 512 float4 (2/thread)
        const int r = tid >> 4, c4 = (tid & 15) * 4;
        *(float4*)&shi[r][c4] = *(const float4*)&hi[((b * Kn) + it * 16 + r) * Hn + c4];
        *(float4*)&shj[r][c4]      = *(const float4*)&hj[((b * Kn) + jt * 32 + r) * Hn + c4];
        *(float4*)&shj[r + 16][c4] = *(const float4*)&hj[((b * Kn) + jt * 32 + r + 16) * Hn + c4];
    }
    if (tid < 16) {
        pix[tid] = positions[((b * Kn) + it * 16 + tid) * 2 + 0];
        piy[tid] = positions[((b * Kn) + it * 16 + tid) * 2 + 1];
    }
    if (tid < 32) {
        pjx[tid] = positions[((b * Kn) + jt * 32 + tid) * 2 + 0];
        pjy[tid] = positions[((b * Kn) + jt * 32 + tid) * 2 + 1];
    }
    const float bb = b2[0];
    __syncthreads();

    const int ti = tid >> 4, tj = tid & 15;

    const f32x2* __restrict__ W2v = (const f32x2*)W2;   // uniform -> SGPR loads

    f32x2 accA0 = {0.f, 0.f}, accB0 = {0.f, 0.f};
    f32x2 accA1 = {0.f, 0.f}, accB1 = {0.f, 0.f};
#pragma unroll
    for (int h = 0; h < Hn; h += 4) {
        const float4 a  = *(const float4*)&shi[ti][h];
        const float4 c0 = *(const float4*)&shj[tj][h];
        const float4 c1 = *(const float4*)&shj[tj + 16][h];
        const f32x2 w0 = W2v[(h >> 1) + 0];
        const f32x2 w1 = W2v[(h >> 1) + 1];
        gelu_dot2((f32x2){a.x, a.y}, (f32x2){c0.x, c0.y}, w0, accA0);
        gelu_dot2((f32x2){a.z, a.w}, (f32x2){c0.z, c0.w}, w1, accB0);
        gelu_dot2((f32x2){a.x, a.y}, (f32x2){c1.x, c1.y}, w0, accA1);
        gelu_dot2((f32x2){a.z, a.w}, (f32x2){c1.z, c1.w}, w1, accB1);
    }
    const f32x2 s0 = accA0 + accB0;
    const f32x2 s1 = accA1 + accB1;
    const float sd0 = s0.x + s0.y + bb;
    const float sd1 = s1.x + s1.y + bb;

    const float dx0 = pix[ti] - pjx[tj],      dy0 = piy[ti] - pjy[tj];
    const float dx1 = pix[ti] - pjx[tj + 16], dy1 = piy[ti] - pjy[tj + 16];
    const float d20 = dx0 * dx0 + dy0 * dy0;
    const float d21 = dx1 * dx1 + dy1 * dy1;
    const float td0 = (d20 > 0.0f) ? sqrtf(d20) : 0.0f;
    const float td1 = (d21 > 0.0f) ? sqrtf(d21) : 0.0f;

    const int i = it * 16 + ti, j0 = jt * 32 + tj;
    out[((b * Kn) + i) * Kn + j0]      = sd0;
    out[((b * Kn) + i) * Kn + j0 + 16] = sd1;

    // deterministic block reduce of squared error (both outputs)
    float v = (sd0 - td0) * (sd0 - td0) + (sd1 - td1) * (sd1 - td1);
#pragma unroll
    for (int off = 32; off > 0; off >>= 1) v += __shfl_down(v, off);
    if ((tid & 63) == 0) wsum[tid >> 6] = v;
    __syncthreads();
    const int bid = (b * gridDim.y + it) * gridDim.x + jt;
    if (tid == 0)
        partials[bid] = (wsum[0] + wsum[1]) + (wsum[2] + wsum[3]);

    // ---- fused final reduction: last block to finish does it ----
    __threadfence();                                   // release partials[bid]
    if (tid == 0)
        last = (atomicAdd(counter, 1u) == NBLK - 1u);
    __syncthreads();
    if (last) {
        __threadfence();                               // acquire all partials
        __shared__ float s[256];
        const float4* p4 = (const float4*)partials;    // 512 float4
        float acc = 0.0f;
#pragma unroll
        for (int k = 0; k < 2; ++k) {
            const float4 x = p4[tid + k * 256];
            acc += (x.x + x.y) + (x.z + x.w);
        }
        s[tid] = acc;
        __syncthreads();
        for (int off = 128; off > 0; off >>= 1) {
            if (tid < off) s[tid] += s[tid + off];
            __syncthreads();
        }
        if (tid == 0)
            loss_out[0] = s[0] * (1.0f / (float)(Bn * Kn * Kn));
    }
}

extern "C" void kernel_launch(void* const* d_in, const int* in_sizes, int n_in,
                              void* d_out, int out_size, void* d_ws, size_t ws_size,
                              hipStream_t stream) {
    const float* particles = (const float*)d_in[0];
    const float* positions = (const float*)d_in[1];
    const float* W1        = (const float*)d_in[2];
    const float* b1        = (const float*)d_in[3];
    const float* W2        = (const float*)d_in[4];
    const float* b2        = (const float*)d_in[5];

    float* out = (float*)d_out;                       // [B*K*K] sd, then [1] loss
    float* ws  = (float*)d_ws;
    float* hi       = ws;                             // B*K*H floats
    float* hj       = ws + Bn * Kn * Hn;
    float* partials = ws + 2 * Bn * Kn * Hn;          // NBLK floats
    unsigned* counter = (unsigned*)(ws + 2 * Bn * Kn * Hn + NBLK);

    kA<<<dim3((Bn * Kn) / 16), dim3(256), 0, stream>>>(particles, W1, b1, hi, hj, counter);
    kB<<<dim3(Kn / 32, Kn / 16, Bn), dim3(256), 0, stream>>>(hi, hj, positions, W2, b2,
                                                             out, partials, counter,
                                                             out + (size_t)Bn * Kn * Kn);
}

// Round 8
// 30.268 us; speedup vs baseline: 6.5267x; 6.5267x over previous
//
#include <hip/hip_runtime.h>
#include <hip/hip_bf16.h>
#include <math.h>

// Problem: B=16, K=256, D=128, H=64
//   hi[b,k,h] = particles[b,k,:] @ W1[:D, h] + b1[h]   (b1 folded here)
//   hj[b,k,h] = particles[b,k,:] @ W1[D:, h]
//   sd[b,i,j] = sum_h gelu(hi[b,i,h] + hj[b,j,h]) * W2[h] + b2
//   loss = mean((sd - true_dist)^2)
// Output: [sd flattened (16*256*256 floats)] [loss (1 float)]
//
// R7 lesson (measured): per-block __threadfence() (device-scope fence) on CDNA4
// costs ~90µs across 2048 blocks (L2 writeback storms; per-XCD L2 non-coherent).
// Loss reduction stays a separate tiny kernel — kernel boundary = cheap coherence.

#define Bn 16
#define Kn 256
#define Dn 128
#define Hn 64
#define NBLK 2048   // kB grid: 8 x 16 x 16

typedef float f32x2 __attribute__((ext_vector_type(2)));
typedef int   i32x2 __attribute__((ext_vector_type(2)));

// Trans-free fast GELU on 2 lanes of packed f32.
//   gelu(x) ~= x * sigmoid(2.3022082*x*(1+0.044715 x^2))
//   exp2 via Schraudolph bit-trick; cubic pre-scaled by 2^23 (folds one mul):
//     u = x*(c1*2^23*x^2 + c0*2^23) + (127-0.0436)*2^23
//   rcp via magic-constant + 1 Newton step
// 9 pk + 4 scalar instrs per 2 h-elements.
__device__ __forceinline__ void gelu_dot2(f32x2 a, f32x2 c, f32x2 w, f32x2& acc) {
    f32x2 x  = a + c;
    f32x2 x2 = x * x;
    f32x2 t1 = __builtin_elementwise_fma(x2, (f32x2)(-863592.7f), (f32x2)(-19312322.0f));
    f32x2 u  = __builtin_elementwise_fma(x, t1, (f32x2)1064987473.0f);
    i32x2 iu = __builtin_convertvector(u, i32x2);          // u in (0, 2^31) for |x|<~9
    f32x2 e  = __builtin_bit_cast(f32x2, iu);              // ~2^t
    f32x2 d  = e + 1.0f;
    i32x2 id = __builtin_bit_cast(i32x2, d);
    i32x2 ir = 0x7EF311C3 - id;
    f32x2 r0 = __builtin_bit_cast(f32x2, ir);
    f32x2 q  = __builtin_elementwise_fma(-d, r0, (f32x2)2.0f);
    f32x2 r  = r0 * q;
    f32x2 g  = x * r;                                      // x * sigmoid
    acc = __builtin_elementwise_fma(g, w, acc);
}

// ---------------- Kernel A: hi/hj precompute ----------------
__global__ __launch_bounds__(256) void kA(const float* __restrict__ particles,
                                          const float* __restrict__ W1,
                                          const float* __restrict__ b1,
                                          float* __restrict__ hi,
                                          float* __restrict__ hj) {
    __shared__ __align__(16) float w1a[Dn * Hn];   // 32 KB  W1[:128]
    __shared__ __align__(16) float w1b[Dn * Hn];   // 32 KB  W1[128:]
    __shared__ __align__(16) float ps[16][Dn];     // 8 KB
    __shared__ __align__(16) float b1s[Hn];

    const int tid = threadIdx.x;
    const int row0 = blockIdx.x * 16;

    for (int idx = tid; idx < (Dn * Hn) / 4; idx += 256) {
        ((float4*)w1a)[idx] = ((const float4*)W1)[idx];
        ((float4*)w1b)[idx] = ((const float4*)(W1 + Dn * Hn))[idx];
    }
    for (int idx = tid; idx < (16 * Dn) / 4; idx += 256)
        ((float4*)&ps[0][0])[idx] = ((const float4*)(particles + row0 * Dn))[idx];
    if (tid < Hn / 4)
        ((float4*)b1s)[tid] = ((const float4*)b1)[tid];
    __syncthreads();

    const int r  = tid >> 4;
    const int h0 = (tid & 15) * 4;

    float4 ai = {0.f, 0.f, 0.f, 0.f};
    float4 aj = {0.f, 0.f, 0.f, 0.f};
#pragma unroll 8
    for (int d = 0; d < Dn; ++d) {
        const float p  = ps[r][d];
        const float4 wa = *(const float4*)&w1a[d * Hn + h0];
        const float4 wb = *(const float4*)&w1b[d * Hn + h0];
        ai.x = fmaf(p, wa.x, ai.x); ai.y = fmaf(p, wa.y, ai.y);
        ai.z = fmaf(p, wa.z, ai.z); ai.w = fmaf(p, wa.w, ai.w);
        aj.x = fmaf(p, wb.x, aj.x); aj.y = fmaf(p, wb.y, aj.y);
        aj.z = fmaf(p, wb.z, aj.z); aj.w = fmaf(p, wb.w, aj.w);
    }
    const float4 bb = *(const float4*)&b1s[h0];
    ai.x += bb.x; ai.y += bb.y; ai.z += bb.z; ai.w += bb.w;

    *(float4*)&hi[(row0 + r) * Hn + h0] = ai;
    *(float4*)&hj[(row0 + r) * Hn + h0] = aj;
}

// ---------------- Kernel B: main pairwise kernel ----------------
// grid (K/32, K/16, B) = (8,16,16), 256 threads.
// Thread (ti = tid>>4, tj = tid&15) computes 2 outputs: j = jt*32 + tj and + 16.
// The shi row read (ds_read_b128) is shared by both outputs.
__global__ __launch_bounds__(256) void kB(const float* __restrict__ hi,
                                          const float* __restrict__ hj,
                                          const float* __restrict__ positions,
                                          const float* __restrict__ W2,
                                          const float* __restrict__ b2,
                                          float* __restrict__ out,
                                          float* __restrict__ partials) {
    __shared__ __align__(16) float shi[16][68];
    __shared__ __align__(16) float shj[32][68];
    __shared__ float pix[16], piy[16], pjx[32], pjy[32];
    __shared__ float wsum[4];

    const int jt = blockIdx.x, it = blockIdx.y, b = blockIdx.z;
    const int tid = threadIdx.x;

    {   // stage: shi 256 float4 (1/thread), shj 512 float4 (2/thread)
        const int r = tid >> 4, c4 = (tid & 15) * 4;
        *(float4*)&shi[r][c4] = *(const float4*)&hi[((b * Kn) + it * 16 + r) * Hn + c4];
        *(float4*)&shj[r][c4]      = *(const float4*)&hj[((b * Kn) + jt * 32 + r) * Hn + c4];
        *(float4*)&shj[r + 16][c4] = *(const float4*)&hj[((b * Kn) + jt * 32 + r + 16) * Hn + c4];
    }
    if (tid < 16) {
        pix[tid] = positions[((b * Kn) + it * 16 + tid) * 2 + 0];
        piy[tid] = positions[((b * Kn) + it * 16 + tid) * 2 + 1];
    }
    if (tid < 32) {
        pjx[tid] = positions[((b * Kn) + jt * 32 + tid) * 2 + 0];
        pjy[tid] = positions[((b * Kn) + jt * 32 + tid) * 2 + 1];
    }
    const float bb = b2[0];
    __syncthreads();

    const int ti = tid >> 4, tj = tid & 15;

    const f32x2* __restrict__ W2v = (const f32x2*)W2;   // uniform -> SGPR loads

    f32x2 accA0 = {0.f, 0.f}, accB0 = {0.f, 0.f};
    f32x2 accA1 = {0.f, 0.f}, accB1 = {0.f, 0.f};
#pragma unroll
    for (int h = 0; h < Hn; h += 4) {
        const float4 a  = *(const float4*)&shi[ti][h];
        const float4 c0 = *(const float4*)&shj[tj][h];
        const float4 c1 = *(const float4*)&shj[tj + 16][h];
        const f32x2 w0 = W2v[(h >> 1) + 0];
        const f32x2 w1 = W2v[(h >> 1) + 1];
        gelu_dot2((f32x2){a.x, a.y}, (f32x2){c0.x, c0.y}, w0, accA0);
        gelu_dot2((f32x2){a.z, a.w}, (f32x2){c0.z, c0.w}, w1, accB0);
        gelu_dot2((f32x2){a.x, a.y}, (f32x2){c1.x, c1.y}, w0, accA1);
        gelu_dot2((f32x2){a.z, a.w}, (f32x2){c1.z, c1.w}, w1, accB1);
    }
    const f32x2 s0 = accA0 + accB0;
    const f32x2 s1 = accA1 + accB1;
    const float sd0 = s0.x + s0.y + bb;
    const float sd1 = s1.x + s1.y + bb;

    const float dx0 = pix[ti] - pjx[tj],      dy0 = piy[ti] - pjy[tj];
    const float dx1 = pix[ti] - pjx[tj + 16], dy1 = piy[ti] - pjy[tj + 16];
    const float d20 = dx0 * dx0 + dy0 * dy0;
    const float d21 = dx1 * dx1 + dy1 * dy1;
    const float td0 = (d20 > 0.0f) ? sqrtf(d20) : 0.0f;
    const float td1 = (d21 > 0.0f) ? sqrtf(d21) : 0.0f;

    const int i = it * 16 + ti, j0 = jt * 32 + tj;
    out[((b * Kn) + i) * Kn + j0]      = sd0;
    out[((b * Kn) + i) * Kn + j0 + 16] = sd1;

    // deterministic block reduce of squared error (both outputs)
    float v = (sd0 - td0) * (sd0 - td0) + (sd1 - td1) * (sd1 - td1);
#pragma unroll
    for (int off = 32; off > 0; off >>= 1) v += __shfl_down(v, off);
    if ((tid & 63) == 0) wsum[tid >> 6] = v;
    __syncthreads();
    if (tid == 0) {
        const int bid = (b * gridDim.y + it) * gridDim.x + jt;
        partials[bid] = (wsum[0] + wsum[1]) + (wsum[2] + wsum[3]);
    }
}

// ---------------- Kernel C: final loss reduction (deterministic order) ----------------
__global__ __launch_bounds__(256) void kC(const float* __restrict__ partials,
                                          float* __restrict__ loss_out) {
    __shared__ float s[256];
    const int tid = threadIdx.x;
    const float4* p4 = (const float4*)partials;        // NBLK/4 = 512 float4
    float v = 0.0f;
#pragma unroll
    for (int k = 0; k < 2; ++k) {
        const float4 x = p4[tid + k * 256];
        v += (x.x + x.y) + (x.z + x.w);
    }
    s[tid] = v;
    __syncthreads();
    for (int off = 128; off > 0; off >>= 1) {
        if (tid < off) s[tid] += s[tid + off];
        __syncthreads();
    }
    if (tid == 0)
        loss_out[0] = s[0] * (1.0f / (float)(Bn * Kn * Kn));
}

extern "C" void kernel_launch(void* const* d_in, const int* in_sizes, int n_in,
                              void* d_out, int out_size, void* d_ws, size_t ws_size,
                              hipStream_t stream) {
    const float* particles = (const float*)d_in[0];
    const float* positions = (const float*)d_in[1];
    const float* W1        = (const float*)d_in[2];
    const float* b1        = (const float*)d_in[3];
    const float* W2        = (const float*)d_in[4];
    const float* b2        = (const float*)d_in[5];

    float* out = (float*)d_out;                       // [B*K*K] sd, then [1] loss
    float* ws  = (float*)d_ws;
    float* hi       = ws;                             // B*K*H floats
    float* hj       = ws + Bn * Kn * Hn;
    float* partials = ws + 2 * Bn * Kn * Hn;          // NBLK floats

    kA<<<dim3((Bn * Kn) / 16), dim3(256), 0, stream>>>(particles, W1, b1, hi, hj);
    kB<<<dim3(Kn / 32, Kn / 16, Bn), dim3(256), 0, stream>>>(hi, hj, positions, W2, b2,
                                                             out, partials);
    kC<<<dim3(1), dim3(256), 0, stream>>>(partials, out + (size_t)Bn * Kn * Kn);
}